// Round 11
// baseline (899.057 us; speedup 1.0000x reference)
//
#include <hip/hip_runtime.h>
#include <math.h>

// B=32, S=256, NU=4, ML=9, H=768, V=30522; T = NU*ML = 36; M = B*T = 1152.
#define BB_ 32
#define SS_ 256
#define HH_ 768
#define VV_ 30522
#define TT_ 36
#define MM_ 1152
#define NBLK_GRU 24

// cvt_all segment prefix boundaries (in float4 units)
#define CE0 5860224   // embed: 30522*768/4
#define CE1 7433088   // + enc: 32*256*768/4
#define CE2 7875456   // + wih: 2304*768/4
#define CE3 8317824   // + whh: 2304*768/4
#define CE4 8323968   // + hidden: 32*768/4

typedef __bf16 bf16x8 __attribute__((ext_vector_type(8)));
typedef __bf16 bf16x4 __attribute__((ext_vector_type(4)));
typedef float f32x4 __attribute__((ext_vector_type(4)));
typedef float f32x2 __attribute__((ext_vector_type(2)));
typedef unsigned int u32x4 __attribute__((ext_vector_type(4)));

__device__ __forceinline__ float sigmoidf_(float x) { return 1.f / (1.f + expf(-x)); }

// async global->LDS, 16B per lane; LDS dest is wave-uniform base + lane*16
__device__ __forceinline__ void async_load16(const void* g, void* l) {
  __builtin_amdgcn_global_load_lds(
      (const __attribute__((address_space(1))) void*)g,
      (__attribute__((address_space(3))) void*)l, 16, 0, 0);
}

// ---------------- fused fp32 -> bf16 conversions (1 launch for 5 tensors) -------
__global__ __launch_bounds__(256) void cvt_all(const float* __restrict__ s0,
                                               const float* __restrict__ s1,
                                               const float* __restrict__ s2,
                                               const float* __restrict__ s3,
                                               const float* __restrict__ s4,
                                               __bf16* __restrict__ d0,
                                               __bf16* __restrict__ d1,
                                               __bf16* __restrict__ d2,
                                               __bf16* __restrict__ d3,
                                               __bf16* __restrict__ d4) {
  int i = blockIdx.x * 256 + threadIdx.x;
  const float* s; __bf16* d; int off;
  if (i < CE0)      { s = s0; d = d0; off = 0; }
  else if (i < CE1) { s = s1; d = d1; off = CE0; }
  else if (i < CE2) { s = s2; d = d2; off = CE1; }
  else if (i < CE3) { s = s3; d = d3; off = CE2; }
  else if (i < CE4) { s = s4; d = d4; off = CE3; }
  else return;
  int j = i - off;
  float4 v = reinterpret_cast<const float4*>(s)[j];
  bf16x4 o;
  o[0] = (__bf16)v.x; o[1] = (__bf16)v.y; o[2] = (__bf16)v.z; o[3] = (__bf16)v.w;
  reinterpret_cast<bf16x4*>(d)[j] = o;
}

// ---------------- build step inputs ws[tau*32+b][k] (bf16) ----------------
__global__ __launch_bounds__(256) void build_ws(const float* __restrict__ dec,
                                                const int* __restrict__ teacher,
                                                const float* __restrict__ embed,
                                                __bf16* __restrict__ wsbf) {
  int idx = blockIdx.x * 256 + threadIdx.x;
  if (idx >= MM_ * HH_) return;
  int m = idx / HH_, k = idx - m * HH_;
  int tau = m >> 5, b = m & 31;
  int u = tau / 9, tt = tau - u * 9;
  float v;
  if (tt == 0) v = dec[((size_t)b * 4 + u) * HH_ + k];
  else v = embed[(size_t)teacher[(b * 4 + u) * 9 + tt - 1] * HH_ + k];
  wsbf[idx] = (__bf16)v;
}

// ---------------- encg[b][s] = enc[b][s][:] . wgen[1536:2304] ----------------
__global__ __launch_bounds__(256) void enc_gate(const float* __restrict__ enc,
                                                const float* __restrict__ wgen,
                                                float* __restrict__ encg) {
  int row = blockIdx.x * 4 + (threadIdx.x >> 6);
  int lane = threadIdx.x & 63;
  const float* er = enc + (size_t)row * HH_;
  float ssum = 0.f;
#pragma unroll
  for (int i = 0; i < 12; ++i) ssum += er[i * 64 + lane] * wgen[1536 + i * 64 + lane];
  for (int off = 32; off; off >>= 1) ssum += __shfl_down(ssum, off);
  if (lane == 0) encg[row] = ssum;
}

// ---------------- m97-style bf16 GEMM: C[M][ldC] = A[M][768] * B[N][768]^T ----------------
// MODE 0: store fp32. MODE 1: nontemporal-store exp(min(c,60)) + atomic row-sum.
template <int MODE>
__global__ __launch_bounds__(256) void gemm_bt2(const __bf16* __restrict__ A,
                                                const __bf16* __restrict__ Bm,
                                                float* __restrict__ C,
                                                float* __restrict__ rowsum,
                                                int Nreal, int ldC) {
  __shared__ __bf16 As[128 * 32];
  __shared__ __bf16 Bs[128 * 32];
  const int tid = threadIdx.x;
  const int lane = tid & 63, wave = tid >> 6;
  const int wm = wave >> 1, wn = wave & 1;
  const int q = lane >> 4, ln = lane & 15;
  const int m0 = blockIdx.y * 128, n0 = blockIdx.x * 128;
  const int srow = (wave << 5) + (lane >> 2);
  const int kc = lane & 3;
  const size_t aoff = (size_t)(m0 + srow) * HH_ + kc * 8;
  const size_t aoff2 = aoff + 16 * HH_;
  int br1 = n0 + srow;      if (br1 >= Nreal) br1 = Nreal - 1;
  int br2 = n0 + srow + 16; if (br2 >= Nreal) br2 = Nreal - 1;
  __bf16* lA1 = &As[srow * 32 + kc * 8];
  __bf16* lA2 = &As[(srow + 16) * 32 + kc * 8];
  __bf16* lB1 = &Bs[srow * 32 + kc * 8];
  __bf16* lB2 = &Bs[(srow + 16) * 32 + kc * 8];
  f32x4 acc[4][4] = {};
  for (int kb = 0; kb < 24; ++kb) {
    const int k0 = kb << 5;
    async_load16(A + aoff + k0, lA1);
    async_load16(A + aoff2 + k0, lA2);
    async_load16(Bm + (size_t)br1 * HH_ + kc * 8 + k0, lB1);
    async_load16(Bm + (size_t)br2 * HH_ + kc * 8 + k0, lB2);
    __syncthreads();
    bf16x8 af[4], bfr[4];
#pragma unroll
    for (int mi = 0; mi < 4; ++mi)
      af[mi] = *reinterpret_cast<const bf16x8*>(&As[(wm * 64 + mi * 16 + ln) * 32 + q * 8]);
#pragma unroll
    for (int ni = 0; ni < 4; ++ni)
      bfr[ni] = *reinterpret_cast<const bf16x8*>(&Bs[(wn * 64 + ni * 16 + ln) * 32 + q * 8]);
#pragma unroll
    for (int mi = 0; mi < 4; ++mi)
#pragma unroll
      for (int ni = 0; ni < 4; ++ni)
        acc[mi][ni] = __builtin_amdgcn_mfma_f32_16x16x32_bf16(af[mi], bfr[ni], acc[mi][ni], 0, 0, 0);
    __syncthreads();
  }
#pragma unroll
  for (int mi = 0; mi < 4; ++mi)
#pragma unroll
    for (int r2 = 0; r2 < 4; ++r2) {
      const int m = m0 + wm * 64 + mi * 16 + q * 4 + r2;
      if (MODE == 0) {
#pragma unroll
        for (int ni = 0; ni < 4; ++ni) {
          int n = n0 + wn * 64 + ni * 16 + ln;
          if (n < Nreal) C[(size_t)m * ldC + n] = acc[mi][ni][r2];
        }
      } else {
        float part = 0.f;
#pragma unroll
        for (int ni = 0; ni < 4; ++ni) {
          int n = n0 + wn * 64 + ni * 16 + ln;
          float e = expf(fminf(acc[mi][ni][r2], 60.f));
          if (n < Nreal) {
            __builtin_nontemporal_store(e, &C[(size_t)m * ldC + n]);
            part += e;
          }
        }
#pragma unroll
        for (int o = 1; o < 16; o <<= 1) part += __shfl_xor(part, o);
        if (ln == 0) atomicAdd(rowsum + m, part);
      }
    }
}

// ---------------- persistent GRU scan v7: 24 blocks x 32 columns ----------------
// Halves the sync radius vs v5 (48 blocks): max-of-24 producer skew, 24-line
// flag gathers, 48 polling waves. Whh slice = 96 rows x 768 (147,456 B LDS).
// Protocol identical to v5 (proven): sc1 consumer loads, per-wave vmcnt drain +
// per-(block,wave) relaxed flag, no fence, no __syncthreads in the loop.
__global__ __launch_bounds__(128, 1) void gru_scan(const __bf16* __restrict__ hid_bf,
                                                   const float* __restrict__ H0,
                                                   const __bf16* __restrict__ Whh,
                                                   const float* __restrict__ GI,
                                                   const float* __restrict__ bih,
                                                   const float* __restrict__ bhh,
                                                   __bf16* __restrict__ Ah,
                                                   __bf16* __restrict__ Hx,
                                                   unsigned* __restrict__ flags) {
  __shared__ __bf16 WhhS[96 * HH_];   // 147,456 B (<= 160 KiB)
  const int tid = threadIdx.x, lane = tid & 63;
  const int mi = tid >> 6;            // wave id: b-half (rows mi*16 .. +16)
  const int q = lane >> 4, ln = lane & 15;
  const int jB = blockIdx.x * 32;
  // stage Whh rows [g*768 + jB + jl] -> LDS row g*32+jl, chunk cs at cs^(row&7)
  for (int i = tid; i < 96 * 96; i += 128) {
    int row = i / 96, cs = i - row * 96;
    int g = row >> 5, jl = row & 31;
    bf16x8 v = *reinterpret_cast<const bf16x8*>(
        &Whh[((size_t)(g * 768 + jB + jl)) * HH_ + cs * 8]);
    *reinterpret_cast<bf16x8*>(&WhhS[row * HH_ + ((cs ^ (row & 7)) * 8)]) = v;
  }
  const int jH0 = jB + ln, jH1 = jB + 16 + ln;
  const float bir[2] = {bih[jH0], bih[jH1]};
  const float biz[2] = {bih[jH0 + 768], bih[jH1 + 768]};
  const float bin_[2] = {bih[jH0 + 1536], bih[jH1 + 1536]};
  const float bhr[2] = {bhh[jH0], bhh[jH1]};
  const float bhz[2] = {bhh[jH0 + 768], bhh[jH1 + 768]};
  const float bhn[2] = {bhh[jH0 + 1536], bhh[jH1 + 1536]};
  // carry h in registers: thread owns (b = mi*16+q*4+r2) x cols {jH0, jH1}
  float hc[4][2];
#pragma unroll
  for (int r2 = 0; r2 < 4; ++r2) {
    hc[r2][0] = H0[(size_t)(mi * 16 + q * 4 + r2) * HH_ + jH0];
    hc[r2][1] = H0[(size_t)(mi * 16 + q * 4 + r2) * HH_ + jH1];
  }
  // 6 LDS row bases: [gate g][colgroup cg]
  const __bf16* wp[3][2];
#pragma unroll
  for (int g = 0; g < 3; ++g) {
    wp[g][0] = &WhhS[(g * 32 + 0 + ln) * HH_];
    wp[g][1] = &WhhS[(g * 32 + 16 + ln) * HH_];
  }
  const int swz = (ln & 7) * 8;       // XOR swizzle in bf16 units (chunk^= ln&7)
  float gir[4][2], giz[4][2], gin[4][2];
#pragma unroll
  for (int r2 = 0; r2 < 4; ++r2) {
    const float* gi = GI + (size_t)(mi * 16 + q * 4 + r2) * 2304;
    gir[r2][0] = gi[jH0]; gir[r2][1] = gi[jH1];
    giz[r2][0] = gi[jH0 + 768]; giz[r2][1] = gi[jH1 + 768];
    gin[r2][0] = gi[jH0 + 1536]; gin[r2][1] = gi[jH1 + 1536];
  }
  __syncthreads();   // WhhS ready — the only barrier in this kernel
  for (int tau = 0; tau < TT_; ++tau) {
    const __bf16* arow = tau ? (Hx + (size_t)(((tau - 1) & 1) * 32 + mi * 16 + ln) * HH_)
                             : (hid_bf + (size_t)(mi * 16 + ln) * HH_);
    u32x4 raw[24];
#pragma unroll
    for (int kb = 0; kb < 24; ++kb) {
      const __bf16* ap = arow + kb * 32 + q * 8;
      asm volatile("global_load_dwordx4 %0, %1, off sc1"
                   : "=v"(raw[kb]) : "v"(ap) : "memory");
    }
    asm volatile("s_waitcnt vmcnt(0)" ::: "memory");
    __builtin_amdgcn_sched_barrier(0);
    f32x4 acc[3][2] = {};
#pragma unroll
    for (int kb = 0; kb < 24; ++kb) {
      bf16x8 a = __builtin_bit_cast(bf16x8, raw[kb]);
      int kl = (kb * 32 + q * 8) ^ swz;
#pragma unroll
      for (int g = 0; g < 3; ++g) {
        bf16x8 b0 = *reinterpret_cast<const bf16x8*>(wp[g][0] + kl);
        bf16x8 b1 = *reinterpret_cast<const bf16x8*>(wp[g][1] + kl);
        acc[g][0] = __builtin_amdgcn_mfma_f32_16x16x32_bf16(a, b0, acc[g][0], 0, 0, 0);
        acc[g][1] = __builtin_amdgcn_mfma_f32_16x16x32_bf16(a, b1, acc[g][1], 0, 0, 0);
      }
    }
    __bf16* hxc = Hx + (size_t)((tau & 1) * 32) * HH_;
#pragma unroll
    for (int r2 = 0; r2 < 4; ++r2) {
      int b = mi * 16 + q * 4 + r2;
#pragma unroll
      for (int cg = 0; cg < 2; ++cg) {
        float r = sigmoidf_(gir[r2][cg] + bir[cg] + acc[0][cg][r2] + bhr[cg]);
        float z = sigmoidf_(giz[r2][cg] + biz[cg] + acc[1][cg][r2] + bhz[cg]);
        float n = tanhf(gin[r2][cg] + bin_[cg] + r * (acc[2][cg][r2] + bhn[cg]));
        float h = (1.f - z) * n + z * hc[r2][cg];
        hc[r2][cg] = h;
        int jH = jB + cg * 16 + ln;
        float hp = __shfl_xor(h, 1);
        __bf16 hb = (__bf16)h, hpb = (__bf16)hp;
        unsigned lo = (unsigned)__builtin_bit_cast(unsigned short, hb);
        unsigned hi = (unsigned)__builtin_bit_cast(unsigned short, hpb);
        if (!(ln & 1)) {
          unsigned u = lo | (hi << 16);
          *reinterpret_cast<unsigned*>(&Ah[((size_t)b * TT_ + tau) * HH_ + jH]) = u;
          if (tau < TT_ - 1)
            __hip_atomic_store(reinterpret_cast<unsigned*>(&hxc[(size_t)b * HH_ + jH]), u,
                               __ATOMIC_RELAXED, __HIP_MEMORY_SCOPE_AGENT);
        }
      }
    }
    if (tau < TT_ - 1) {
      asm volatile("s_waitcnt vmcnt(0)" ::: "memory");
      if (lane == 0)
        __hip_atomic_store(&flags[(size_t)(blockIdx.x * 2 + mi) * 16], (unsigned)(tau + 1),
                           __ATOMIC_RELAXED, __HIP_MEMORY_SCOPE_AGENT);
      {
        const float* GIt = GI + (size_t)(tau + 1) * BB_ * 2304;
#pragma unroll
        for (int r2 = 0; r2 < 4; ++r2) {
          const float* gi = GIt + (size_t)(mi * 16 + q * 4 + r2) * 2304;
          gir[r2][0] = gi[jH0]; gir[r2][1] = gi[jH1];
          giz[r2][0] = gi[jH0 + 768]; giz[r2][1] = gi[jH1 + 768];
          gin[r2][0] = gi[jH0 + 1536]; gin[r2][1] = gi[jH1 + 1536];
        }
      }
      const unsigned tgt = (unsigned)(tau + 1);
      int ok = 0, spin = 0;
      while (!ok) {
        unsigned v = (lane < NBLK_GRU)
            ? __hip_atomic_load(&flags[(size_t)(lane * 2 + mi) * 16], __ATOMIC_RELAXED,
                                __HIP_MEMORY_SCOPE_AGENT)
            : tgt;
        ok = __all((int)(v >= tgt));
        if (!ok) {
          __builtin_amdgcn_s_sleep(1);
          if (++spin > (1 << 20)) break;   // fail loud, don't wedge
        }
      }
    }
  }
}

// ---------------- attention scores E[b*36+tau][s] (batched MFMA) ----------------
__global__ __launch_bounds__(256) void attn_gemm(const __bf16* __restrict__ Ah,
                                                 const __bf16* __restrict__ encb,
                                                 float* __restrict__ E) {
  int b = blockIdx.x >> 2, stile = blockIdx.x & 3;
  int wave = threadIdx.x >> 6, lane = threadIdx.x & 63;
  int q = lane >> 4, ln = lane & 15;
  int s = stile * 64 + wave * 16 + ln;
  const __bf16* brow = encb + ((size_t)b * SS_ + s) * HH_;
  const __bf16* arow[3];
#pragma unroll
  for (int mt = 0; mt < 3; ++mt) {
    int tau = mt * 16 + ln; if (tau > 35) tau = 35;
    arow[mt] = Ah + ((size_t)b * TT_ + tau) * HH_;
  }
  f32x4 acc[3] = {};
#pragma unroll 4
  for (int kb = 0; kb < 24; ++kb) {
    int k0 = kb * 32 + q * 8;
    bf16x8 bb = *reinterpret_cast<const bf16x8*>(brow + k0);
#pragma unroll
    for (int mt = 0; mt < 3; ++mt) {
      bf16x8 aa = *reinterpret_cast<const bf16x8*>(arow[mt] + k0);
      acc[mt] = __builtin_amdgcn_mfma_f32_16x16x32_bf16(aa, bb, acc[mt], 0, 0, 0);
    }
  }
#pragma unroll
  for (int mt = 0; mt < 3; ++mt)
#pragma unroll
    for (int r2 = 0; r2 < 4; ++r2) {
      int tau = mt * 16 + q * 4 + r2;
      if (tau < 36) E[((size_t)b * TT_ + tau) * SS_ + s] = acc[mt][r2];
    }
}

// ---------------- masked softmax over S + p_gen ----------------
__global__ __launch_bounds__(256) void softmax_pg(const float* __restrict__ E,
                                                  const int* __restrict__ x,
                                                  const float* __restrict__ encg,
                                                  const __bf16* __restrict__ wsbf,
                                                  const __bf16* __restrict__ Ah,
                                                  const float* __restrict__ wgen,
                                                  const float* __restrict__ wgenb,
                                                  float* __restrict__ attn,
                                                  float* __restrict__ pg) {
  int m = blockIdx.x;
  int b = m / TT_, tau = m - b * TT_;
  int m_in = tau * 32 + b;
  int t = threadIdx.x;
  __shared__ float red[256];
  __shared__ float r1[256], r2[256], r3[256];
  float e = E[(size_t)m * SS_ + t];
  if (x[b * SS_ + t] == 0) e = -1000000000.0f;
  red[t] = e; __syncthreads();
  for (int off = 128; off; off >>= 1) {
    if (t < off) red[t] = fmaxf(red[t], red[t + off]);
    __syncthreads();
  }
  float mx = red[0];
  float p = expf(e - mx);
  float dsum = 0.f;
#pragma unroll
  for (int i = 0; i < 3; ++i) {
    int k = t + i * 256;
    dsum += (float)wsbf[(size_t)m_in * HH_ + k] * wgen[k];
    dsum += (float)Ah[(size_t)m * HH_ + k] * wgen[768 + k];
  }
  float pe = p * encg[b * SS_ + t];
  r1[t] = p; r2[t] = pe; r3[t] = dsum; __syncthreads();
  for (int off = 128; off; off >>= 1) {
    if (t < off) { r1[t] += r1[t + off]; r2[t] += r2[t + off]; r3[t] += r3[t + off]; }
    __syncthreads();
  }
  float Z = r1[0];
  attn[(size_t)m * SS_ + t] = p / Z;
  if (t == 0) pg[m] = sigmoidf_(r3[0] + r2[0] / Z + wgenb[0]);
}

// ---------------- finalize: out = pg/Z * exp_vals (in place, f32x2 + nt) --------
__global__ __launch_bounds__(256) void finalize(float* __restrict__ C,
                                                const float* __restrict__ rowsum,
                                                const float* __restrict__ pg) {
  int m = blockIdx.y;
  float scale = pg[m] / rowsum[m];
  f32x2* row = reinterpret_cast<f32x2*>(C + (size_t)m * VV_);  // row start 8B-aligned (VV_ even)
#pragma unroll
  for (int j = 0; j < 8; ++j) {
    int i2 = blockIdx.x * 2048 + j * 256 + threadIdx.x;
    if (i2 < VV_ / 2) {
      f32x2 v = __builtin_nontemporal_load(&row[i2]);
      v[0] *= scale; v[1] *= scale;
      __builtin_nontemporal_store(v, &row[i2]);
    }
  }
}

// ---------------- pointer scatter ----------------
__global__ __launch_bounds__(256) void scatter_ctx(float* __restrict__ C,
                                                   const float* __restrict__ attn,
                                                   const float* __restrict__ pg,
                                                   const int* __restrict__ x) {
  int m = blockIdx.x, s = threadIdx.x;
  int b = m / TT_;
  float v = (1.f - pg[m]) * attn[(size_t)m * SS_ + s];
  int col = x[b * SS_ + s];
  atomicAdd(C + (size_t)m * VV_ + col, v);
}

extern "C" void kernel_launch(void* const* d_in, const int* in_sizes, int n_in,
                              void* d_out, int out_size, void* d_ws, size_t ws_size,
                              hipStream_t stream) {
  const int*   x       = (const int*)d_in[0];
  const float* dec     = (const float*)d_in[1];
  const float* enc     = (const float*)d_in[2];
  const float* hidden  = (const float*)d_in[3];
  const int*   teacher = (const int*)d_in[5];
  const float* embed   = (const float*)d_in[6];
  const float* wih     = (const float*)d_in[7];
  const float* whh     = (const float*)d_in[8];
  const float* bih     = (const float*)d_in[9];
  const float* bhh     = (const float*)d_in[10];
  const float* wgen    = (const float*)d_in[11];
  const float* wgenb   = (const float*)d_in[12];
  float* out = (float*)d_out;

  char* w = (char*)d_ws;
  __bf16* embed_bf = (__bf16*)w;  w += (size_t)VV_ * HH_ * 2;
  __bf16* enc_bf   = (__bf16*)w;  w += (size_t)BB_ * SS_ * HH_ * 2;
  __bf16* wih_bf   = (__bf16*)w;  w += (size_t)2304 * HH_ * 2;
  __bf16* whh_bf   = (__bf16*)w;  w += (size_t)2304 * HH_ * 2;
  __bf16* ws_bf    = (__bf16*)w;  w += (size_t)MM_ * HH_ * 2;
  __bf16* hid_bf   = (__bf16*)w;  w += (size_t)BB_ * HH_ * 2;
  __bf16* A_h      = (__bf16*)w;  w += (size_t)MM_ * HH_ * 2;
  float*  GI       = (float*)w;   w += (size_t)MM_ * 2304 * 4;
  float*  E        = (float*)w;   w += (size_t)MM_ * SS_ * 4;
  float*  attn     = (float*)w;   w += (size_t)MM_ * SS_ * 4;
  float*  encg     = (float*)w;   w += (size_t)BB_ * SS_ * 4;
  float*  pg       = (float*)w;   w += 8192;
  char*   ctl      = w;           w += 16384;  // rowsum[1152] + flags[48*16]
  __bf16* Hx       = (__bf16*)w;  w += (size_t)2 * BB_ * HH_ * 2;  // h exchange dbuf
  float*    rowsum = (float*)ctl;
  unsigned* flags  = (unsigned*)(ctl + 4864);

  // 0) zero rowsum + flags (ws is re-poisoned 0xAA before every call)
  hipMemsetAsync(ctl, 0, 16384, stream);

  // 1) all fp32->bf16 conversions in one launch
  cvt_all<<<(CE4 + 255) / 256, 256, 0, stream>>>(embed, enc, wih, whh, hidden,
                                                 embed_bf, enc_bf, wih_bf, whh_bf, hid_bf);

  // 2) step inputs
  build_ws<<<(MM_ * HH_ + 255) / 256, 256, 0, stream>>>(dec, teacher, embed, ws_bf);

  // 3) GI = ws @ Wih^T : M=1152, N=2304, K=768
  gemm_bt2<0><<<dim3(2304 / 128, MM_ / 128), 256, 0, stream>>>(ws_bf, wih_bf, GI, nullptr, 2304, 2304);

  // 4) encg
  enc_gate<<<BB_ * SS_ / 4, 256, 0, stream>>>(enc, wgen, encg);

  // 5) persistent GRU scan (v7: 24 blocks x 32 cols, halved sync radius)
  gru_scan<<<NBLK_GRU, 128, 0, stream>>>(hid_bf, hidden, whh_bf, GI, bih, bhh, A_h, Hx, flags);

  // 6) attention + masked softmax + p_gen
  attn_gemm<<<BB_ * 4, 256, 0, stream>>>(A_h, enc_bf, E);
  softmax_pg<<<MM_, 256, 0, stream>>>(E, x, encg, ws_bf, A_h, wgen, wgenb, attn, pg);

  // 7) vocab logits -> exp (nt stores) into d_out + atomic row sums
  gemm_bt2<1><<<dim3((VV_ + 127) / 128, MM_ / 128), 256, 0, stream>>>(A_h, embed_bf, out, rowsum, VV_, VV_);

  // 8) scale by pg/Z in place (f32x2 + nt), then pointer scatter
  finalize<<<dim3(8, MM_), 256, 0, stream>>>(out, rowsum, pg);
  scatter_ctx<<<MM_, 256, 0, stream>>>(out, attn, pg, x);
}

// Round 12
// 770.901 us; speedup vs baseline: 1.1662x; 1.1662x over previous
//
#include <hip/hip_runtime.h>
#include <math.h>

// B=32, S=256, NU=4, ML=9, H=768, V=30522; T = NU*ML = 36; M = B*T = 1152.
#define BB_ 32
#define SS_ 256
#define HH_ 768
#define VV_ 30522
#define TT_ 36
#define MM_ 1152
#define NBLK_GRU 48

// prep kernel grid partition (in 256-thread blocks)
#define CE0 5860224   // embed: 30522*768/4 (float4 units)
#define CE1 7433088   // + enc: 32*256*768/4
#define CE2 7875456   // + wih: 2304*768/4
#define CE3 8317824   // + whh: 2304*768/4
#define CE4 8323968   // + hidden: 32*768/4
#define PREP_CVT_BLK 32516            // (CE4+255)/256
#define PREP_WS_BLK  3456             // MM_*HH_/256
#define PREP_EG_BLK  2048             // BB_*SS_/4
#define PREP_TOTAL   (PREP_CVT_BLK + PREP_WS_BLK + PREP_EG_BLK)

typedef __bf16 bf16x8 __attribute__((ext_vector_type(8)));
typedef __bf16 bf16x4 __attribute__((ext_vector_type(4)));
typedef float f32x4 __attribute__((ext_vector_type(4)));
typedef float f32x2 __attribute__((ext_vector_type(2)));
typedef unsigned int u32x4 __attribute__((ext_vector_type(4)));

__device__ __forceinline__ float sigmoidf_(float x) { return 1.f / (1.f + expf(-x)); }

// async global->LDS, 16B per lane; LDS dest is wave-uniform base + lane*16
__device__ __forceinline__ void async_load16(const void* g, void* l) {
  __builtin_amdgcn_global_load_lds(
      (const __attribute__((address_space(1))) void*)g,
      (__attribute__((address_space(3))) void*)l, 16, 0, 0);
}

// ---------------- fused preprocessing: cvt x5 + build_ws + enc_gate (1 launch) --
__global__ __launch_bounds__(256) void prep(const float* __restrict__ embed,
                                            const float* __restrict__ enc,
                                            const float* __restrict__ wih,
                                            const float* __restrict__ whh,
                                            const float* __restrict__ hidden,
                                            const float* __restrict__ dec,
                                            const int* __restrict__ teacher,
                                            const float* __restrict__ wgen,
                                            __bf16* __restrict__ embed_bf,
                                            __bf16* __restrict__ enc_bf,
                                            __bf16* __restrict__ wih_bf,
                                            __bf16* __restrict__ whh_bf,
                                            __bf16* __restrict__ hid_bf,
                                            __bf16* __restrict__ wsbf,
                                            float* __restrict__ encg) {
  int bb = blockIdx.x;
  if (bb < PREP_CVT_BLK) {
    // ---- fp32 -> bf16 bulk convert (5 tensors, segment by prefix) ----
    int i = bb * 256 + threadIdx.x;
    const float* s; __bf16* d; int off;
    if (i < CE0)      { s = embed;  d = embed_bf; off = 0; }
    else if (i < CE1) { s = enc;    d = enc_bf;   off = CE0; }
    else if (i < CE2) { s = wih;    d = wih_bf;   off = CE1; }
    else if (i < CE3) { s = whh;    d = whh_bf;   off = CE2; }
    else if (i < CE4) { s = hidden; d = hid_bf;   off = CE3; }
    else return;
    int j = i - off;
    float4 v = reinterpret_cast<const float4*>(s)[j];
    bf16x4 o;
    o[0] = (__bf16)v.x; o[1] = (__bf16)v.y; o[2] = (__bf16)v.z; o[3] = (__bf16)v.w;
    reinterpret_cast<bf16x4*>(d)[j] = o;
  } else if (bb < PREP_CVT_BLK + PREP_WS_BLK) {
    // ---- build step inputs ws[tau*32+b][k] (bf16) ----
    int idx = (bb - PREP_CVT_BLK) * 256 + threadIdx.x;
    int m = idx / HH_, k = idx - m * HH_;
    int tau = m >> 5, b = m & 31;
    int u = tau / 9, tt = tau - u * 9;
    float v;
    if (tt == 0) v = dec[((size_t)b * 4 + u) * HH_ + k];
    else v = embed[(size_t)teacher[(b * 4 + u) * 9 + tt - 1] * HH_ + k];
    wsbf[idx] = (__bf16)v;
  } else {
    // ---- encg[b][s] = enc[b][s][:] . wgen[1536:2304] ----
    int row = (bb - PREP_CVT_BLK - PREP_WS_BLK) * 4 + (threadIdx.x >> 6);
    int lane = threadIdx.x & 63;
    const float* er = enc + (size_t)row * HH_;
    float ssum = 0.f;
#pragma unroll
    for (int i = 0; i < 12; ++i) ssum += er[i * 64 + lane] * wgen[1536 + i * 64 + lane];
    for (int off = 32; off; off >>= 1) ssum += __shfl_down(ssum, off);
    if (lane == 0) encg[row] = ssum;
  }
}

// ---------------- m97-style bf16 GEMM: C[M][ldC] = A[M][768] * B[N][768]^T ----------------
// MODE 0: store fp32. MODE 1: nontemporal-store exp(min(c,60)) + atomic row-sum.
template <int MODE>
__global__ __launch_bounds__(256) void gemm_bt2(const __bf16* __restrict__ A,
                                                const __bf16* __restrict__ Bm,
                                                float* __restrict__ C,
                                                float* __restrict__ rowsum,
                                                int Nreal, int ldC) {
  __shared__ __bf16 As[128 * 32];
  __shared__ __bf16 Bs[128 * 32];
  const int tid = threadIdx.x;
  const int lane = tid & 63, wave = tid >> 6;
  const int wm = wave >> 1, wn = wave & 1;
  const int q = lane >> 4, ln = lane & 15;
  const int m0 = blockIdx.y * 128, n0 = blockIdx.x * 128;
  const int srow = (wave << 5) + (lane >> 2);
  const int kc = lane & 3;
  const size_t aoff = (size_t)(m0 + srow) * HH_ + kc * 8;
  const size_t aoff2 = aoff + 16 * HH_;
  int br1 = n0 + srow;      if (br1 >= Nreal) br1 = Nreal - 1;
  int br2 = n0 + srow + 16; if (br2 >= Nreal) br2 = Nreal - 1;
  __bf16* lA1 = &As[srow * 32 + kc * 8];
  __bf16* lA2 = &As[(srow + 16) * 32 + kc * 8];
  __bf16* lB1 = &Bs[srow * 32 + kc * 8];
  __bf16* lB2 = &Bs[(srow + 16) * 32 + kc * 8];
  f32x4 acc[4][4] = {};
  for (int kb = 0; kb < 24; ++kb) {
    const int k0 = kb << 5;
    async_load16(A + aoff + k0, lA1);
    async_load16(A + aoff2 + k0, lA2);
    async_load16(Bm + (size_t)br1 * HH_ + kc * 8 + k0, lB1);
    async_load16(Bm + (size_t)br2 * HH_ + kc * 8 + k0, lB2);
    __syncthreads();
    bf16x8 af[4], bfr[4];
#pragma unroll
    for (int mi = 0; mi < 4; ++mi)
      af[mi] = *reinterpret_cast<const bf16x8*>(&As[(wm * 64 + mi * 16 + ln) * 32 + q * 8]);
#pragma unroll
    for (int ni = 0; ni < 4; ++ni)
      bfr[ni] = *reinterpret_cast<const bf16x8*>(&Bs[(wn * 64 + ni * 16 + ln) * 32 + q * 8]);
#pragma unroll
    for (int mi = 0; mi < 4; ++mi)
#pragma unroll
      for (int ni = 0; ni < 4; ++ni)
        acc[mi][ni] = __builtin_amdgcn_mfma_f32_16x16x32_bf16(af[mi], bfr[ni], acc[mi][ni], 0, 0, 0);
    __syncthreads();
  }
#pragma unroll
  for (int mi = 0; mi < 4; ++mi)
#pragma unroll
    for (int r2 = 0; r2 < 4; ++r2) {
      const int m = m0 + wm * 64 + mi * 16 + q * 4 + r2;
      if (MODE == 0) {
#pragma unroll
        for (int ni = 0; ni < 4; ++ni) {
          int n = n0 + wn * 64 + ni * 16 + ln;
          if (n < Nreal) C[(size_t)m * ldC + n] = acc[mi][ni][r2];
        }
      } else {
        float part = 0.f;
#pragma unroll
        for (int ni = 0; ni < 4; ++ni) {
          int n = n0 + wn * 64 + ni * 16 + ln;
          float e = expf(fminf(acc[mi][ni][r2], 60.f));
          if (n < Nreal) {
            __builtin_nontemporal_store(e, &C[(size_t)m * ldC + n]);
            part += e;
          }
        }
#pragma unroll
        for (int o = 1; o < 16; o <<= 1) part += __shfl_xor(part, o);
        if (ln == 0) atomicAdd(rowsum + m, part);
      }
    }
}

// ---------------- persistent GRU scan v5 (best measured: 216-230 us) ------------
// 48 blocks x 128. Whh slice XOR-swizzled in LDS; h carried in registers;
// exchange via Hx dbuf (relaxed agent sc1 stores). No fence, no __syncthreads
// in the loop: consumer A-loads are device-scope (sc1) dwordx4; release is
// per-wave vmcnt drain + per-(block,wave) flag; wave mi polls only same-mi flags.
// Six protocol/shape variants bracket this at ~6 us/step — structural floor.
__global__ __launch_bounds__(128, 1) void gru_scan(const __bf16* __restrict__ hid_bf,
                                                   const float* __restrict__ H0,
                                                   const __bf16* __restrict__ Whh,
                                                   const float* __restrict__ GI,
                                                   const float* __restrict__ bih,
                                                   const float* __restrict__ bhh,
                                                   __bf16* __restrict__ Ah,
                                                   __bf16* __restrict__ Hx,
                                                   unsigned* __restrict__ flags) {
  __shared__ __bf16 WhhS[48 * HH_];   // 73,728 B
  const int tid = threadIdx.x, lane = tid & 63;
  const int mi = tid >> 6;            // wave id: b-tile (0:,16:)
  const int q = lane >> 4, ln = lane & 15;
  const int jH = blockIdx.x * 16 + ln;
  for (int i = tid; i < 48 * 96; i += 128) {
    int row = i / 96, cs = i - row * 96;
    int g = row >> 4, jl = row & 15;
    bf16x8 v = *reinterpret_cast<const bf16x8*>(
        &Whh[((size_t)(g * 768 + blockIdx.x * 16 + jl)) * HH_ + cs * 8]);
    *reinterpret_cast<bf16x8*>(&WhhS[row * HH_ + ((cs ^ (row & 7)) * 8)]) = v;
  }
  const float bir = bih[jH], biz = bih[jH + 768], bin_ = bih[jH + 1536];
  const float bhr = bhh[jH], bhz = bhh[jH + 768], bhn = bhh[jH + 1536];
  float hc[4];
#pragma unroll
  for (int r2 = 0; r2 < 4; ++r2)
    hc[r2] = H0[(size_t)(mi * 16 + q * 4 + r2) * HH_ + jH];
  const __bf16* w0 = &WhhS[(0 + ln) * HH_];
  const __bf16* w1 = &WhhS[(16 + ln) * HH_];
  const __bf16* w2 = &WhhS[(32 + ln) * HH_];
  const int swz = (ln & 7) * 8;       // XOR swizzle in bf16 units (chunk^= ln&7)
  float gir[4], giz[4], gin[4];
#pragma unroll
  for (int r2 = 0; r2 < 4; ++r2) {
    const float* gi = GI + (size_t)(mi * 16 + q * 4 + r2) * 2304;
    gir[r2] = gi[jH]; giz[r2] = gi[jH + 768]; gin[r2] = gi[jH + 1536];
  }
  __syncthreads();   // WhhS ready — the only barrier in this kernel
  for (int tau = 0; tau < TT_; ++tau) {
    const __bf16* arow = tau ? (Hx + (size_t)(((tau - 1) & 1) * 32 + mi * 16 + ln) * HH_)
                             : (hid_bf + (size_t)(mi * 16 + ln) * HH_);
    u32x4 raw[24];
#pragma unroll
    for (int kb = 0; kb < 24; ++kb) {
      const __bf16* ap = arow + kb * 32 + q * 8;
      asm volatile("global_load_dwordx4 %0, %1, off sc1"
                   : "=v"(raw[kb]) : "v"(ap) : "memory");
    }
    asm volatile("s_waitcnt vmcnt(0)" ::: "memory");
    __builtin_amdgcn_sched_barrier(0);
    f32x4 a0 = {}, a1 = {}, a2 = {};
#pragma unroll
    for (int kb = 0; kb < 24; ++kb) {
      bf16x8 a = __builtin_bit_cast(bf16x8, raw[kb]);
      int kl = (kb * 32 + q * 8) ^ swz;
      bf16x8 b0 = *reinterpret_cast<const bf16x8*>(w0 + kl);
      bf16x8 b1 = *reinterpret_cast<const bf16x8*>(w1 + kl);
      bf16x8 b2 = *reinterpret_cast<const bf16x8*>(w2 + kl);
      a0 = __builtin_amdgcn_mfma_f32_16x16x32_bf16(a, b0, a0, 0, 0, 0);
      a1 = __builtin_amdgcn_mfma_f32_16x16x32_bf16(a, b1, a1, 0, 0, 0);
      a2 = __builtin_amdgcn_mfma_f32_16x16x32_bf16(a, b2, a2, 0, 0, 0);
    }
    __bf16* hxc = Hx + (size_t)((tau & 1) * 32) * HH_;
#pragma unroll
    for (int r2 = 0; r2 < 4; ++r2) {
      int b = mi * 16 + q * 4 + r2;
      float r = sigmoidf_(gir[r2] + bir + a0[r2] + bhr);
      float z = sigmoidf_(giz[r2] + biz + a1[r2] + bhz);
      float n = tanhf(gin[r2] + bin_ + r * (a2[r2] + bhn));
      float h = (1.f - z) * n + z * hc[r2];
      hc[r2] = h;
      float hp = __shfl_xor(h, 1);
      __bf16 hb = (__bf16)h, hpb = (__bf16)hp;
      unsigned lo = (unsigned)__builtin_bit_cast(unsigned short, hb);
      unsigned hi = (unsigned)__builtin_bit_cast(unsigned short, hpb);
      if (!(ln & 1)) {
        unsigned u = lo | (hi << 16);
        *reinterpret_cast<unsigned*>(&Ah[((size_t)b * TT_ + tau) * HH_ + jH]) = u;
        if (tau < TT_ - 1)
          __hip_atomic_store(reinterpret_cast<unsigned*>(&hxc[(size_t)b * HH_ + jH]), u,
                             __ATOMIC_RELAXED, __HIP_MEMORY_SCOPE_AGENT);
      }
    }
    if (tau < TT_ - 1) {
      asm volatile("s_waitcnt vmcnt(0)" ::: "memory");
      if (lane == 0)
        __hip_atomic_store(&flags[(size_t)(blockIdx.x * 2 + mi) * 16], (unsigned)(tau + 1),
                           __ATOMIC_RELAXED, __HIP_MEMORY_SCOPE_AGENT);
      {
        const float* GIt = GI + (size_t)(tau + 1) * BB_ * 2304;
#pragma unroll
        for (int r2 = 0; r2 < 4; ++r2) {
          const float* gi = GIt + (size_t)(mi * 16 + q * 4 + r2) * 2304;
          gir[r2] = gi[jH]; giz[r2] = gi[jH + 768]; gin[r2] = gi[jH + 1536];
        }
      }
      const unsigned tgt = (unsigned)(tau + 1);
      int ok = 0, spin = 0;
      while (!ok) {
        unsigned v = (lane < NBLK_GRU)
            ? __hip_atomic_load(&flags[(size_t)(lane * 2 + mi) * 16], __ATOMIC_RELAXED,
                                __HIP_MEMORY_SCOPE_AGENT)
            : tgt;
        ok = __all((int)(v >= tgt));
        if (!ok) {
          __builtin_amdgcn_s_sleep(1);
          if (++spin > (1 << 20)) break;   // fail loud, don't wedge
        }
      }
    }
  }
}

// ---------------- attention scores E[b*36+tau][s] (batched MFMA) ----------------
__global__ __launch_bounds__(256) void attn_gemm(const __bf16* __restrict__ Ah,
                                                 const __bf16* __restrict__ encb,
                                                 float* __restrict__ E) {
  int b = blockIdx.x >> 2, stile = blockIdx.x & 3;
  int wave = threadIdx.x >> 6, lane = threadIdx.x & 63;
  int q = lane >> 4, ln = lane & 15;
  int s = stile * 64 + wave * 16 + ln;
  const __bf16* brow = encb + ((size_t)b * SS_ + s) * HH_;
  const __bf16* arow[3];
#pragma unroll
  for (int mt = 0; mt < 3; ++mt) {
    int tau = mt * 16 + ln; if (tau > 35) tau = 35;
    arow[mt] = Ah + ((size_t)b * TT_ + tau) * HH_;
  }
  f32x4 acc[3] = {};
#pragma unroll 4
  for (int kb = 0; kb < 24; ++kb) {
    int k0 = kb * 32 + q * 8;
    bf16x8 bb = *reinterpret_cast<const bf16x8*>(brow + k0);
#pragma unroll
    for (int mt = 0; mt < 3; ++mt) {
      bf16x8 aa = *reinterpret_cast<const bf16x8*>(arow[mt] + k0);
      acc[mt] = __builtin_amdgcn_mfma_f32_16x16x32_bf16(aa, bb, acc[mt], 0, 0, 0);
    }
  }
#pragma unroll
  for (int mt = 0; mt < 3; ++mt)
#pragma unroll
    for (int r2 = 0; r2 < 4; ++r2) {
      int tau = mt * 16 + q * 4 + r2;
      if (tau < 36) E[((size_t)b * TT_ + tau) * SS_ + s] = acc[mt][r2];
    }
}

// ---------------- masked softmax over S + p_gen ----------------
__global__ __launch_bounds__(256) void softmax_pg(const float* __restrict__ E,
                                                  const int* __restrict__ x,
                                                  const float* __restrict__ encg,
                                                  const __bf16* __restrict__ wsbf,
                                                  const __bf16* __restrict__ Ah,
                                                  const float* __restrict__ wgen,
                                                  const float* __restrict__ wgenb,
                                                  float* __restrict__ attn,
                                                  float* __restrict__ pg) {
  int m = blockIdx.x;
  int b = m / TT_, tau = m - b * TT_;
  int m_in = tau * 32 + b;
  int t = threadIdx.x;
  __shared__ float red[256];
  __shared__ float r1[256], r2[256], r3[256];
  float e = E[(size_t)m * SS_ + t];
  if (x[b * SS_ + t] == 0) e = -1000000000.0f;
  red[t] = e; __syncthreads();
  for (int off = 128; off; off >>= 1) {
    if (t < off) red[t] = fmaxf(red[t], red[t + off]);
    __syncthreads();
  }
  float mx = red[0];
  float p = expf(e - mx);
  float dsum = 0.f;
#pragma unroll
  for (int i = 0; i < 3; ++i) {
    int k = t + i * 256;
    dsum += (float)wsbf[(size_t)m_in * HH_ + k] * wgen[k];
    dsum += (float)Ah[(size_t)m * HH_ + k] * wgen[768 + k];
  }
  float pe = p * encg[b * SS_ + t];
  r1[t] = p; r2[t] = pe; r3[t] = dsum; __syncthreads();
  for (int off = 128; off; off >>= 1) {
    if (t < off) { r1[t] += r1[t + off]; r2[t] += r2[t + off]; r3[t] += r3[t + off]; }
    __syncthreads();
  }
  float Z = r1[0];
  attn[(size_t)m * SS_ + t] = p / Z;
  if (t == 0) pg[m] = sigmoidf_(r3[0] + r2[0] / Z + wgenb[0]);
}

// ---------------- finalize: out = pg/Z * exp_vals (in place, f32x2 + nt) --------
__global__ __launch_bounds__(256) void finalize(float* __restrict__ C,
                                                const float* __restrict__ rowsum,
                                                const float* __restrict__ pg) {
  int m = blockIdx.y;
  float scale = pg[m] / rowsum[m];
  f32x2* row = reinterpret_cast<f32x2*>(C + (size_t)m * VV_);  // row start 8B-aligned (VV_ even)
#pragma unroll
  for (int j = 0; j < 8; ++j) {
    int i2 = blockIdx.x * 2048 + j * 256 + threadIdx.x;
    if (i2 < VV_ / 2) {
      f32x2 v = __builtin_nontemporal_load(&row[i2]);
      v[0] *= scale; v[1] *= scale;
      __builtin_nontemporal_store(v, &row[i2]);
    }
  }
}

// ---------------- pointer scatter ----------------
__global__ __launch_bounds__(256) void scatter_ctx(float* __restrict__ C,
                                                   const float* __restrict__ attn,
                                                   const float* __restrict__ pg,
                                                   const int* __restrict__ x) {
  int m = blockIdx.x, s = threadIdx.x;
  int b = m / TT_;
  float v = (1.f - pg[m]) * attn[(size_t)m * SS_ + s];
  int col = x[b * SS_ + s];
  atomicAdd(C + (size_t)m * VV_ + col, v);
}

extern "C" void kernel_launch(void* const* d_in, const int* in_sizes, int n_in,
                              void* d_out, int out_size, void* d_ws, size_t ws_size,
                              hipStream_t stream) {
  const int*   x       = (const int*)d_in[0];
  const float* dec     = (const float*)d_in[1];
  const float* enc     = (const float*)d_in[2];
  const float* hidden  = (const float*)d_in[3];
  const int*   teacher = (const int*)d_in[5];
  const float* embed   = (const float*)d_in[6];
  const float* wih     = (const float*)d_in[7];
  const float* whh     = (const float*)d_in[8];
  const float* bih     = (const float*)d_in[9];
  const float* bhh     = (const float*)d_in[10];
  const float* wgen    = (const float*)d_in[11];
  const float* wgenb   = (const float*)d_in[12];
  float* out = (float*)d_out;

  char* w = (char*)d_ws;
  __bf16* embed_bf = (__bf16*)w;  w += (size_t)VV_ * HH_ * 2;
  __bf16* enc_bf   = (__bf16*)w;  w += (size_t)BB_ * SS_ * HH_ * 2;
  __bf16* wih_bf   = (__bf16*)w;  w += (size_t)2304 * HH_ * 2;
  __bf16* whh_bf   = (__bf16*)w;  w += (size_t)2304 * HH_ * 2;
  __bf16* ws_bf    = (__bf16*)w;  w += (size_t)MM_ * HH_ * 2;
  __bf16* hid_bf   = (__bf16*)w;  w += (size_t)BB_ * HH_ * 2;
  __bf16* A_h      = (__bf16*)w;  w += (size_t)MM_ * HH_ * 2;
  float*  GI       = (float*)w;   w += (size_t)MM_ * 2304 * 4;
  float*  E        = (float*)w;   w += (size_t)MM_ * SS_ * 4;
  float*  attn     = (float*)w;   w += (size_t)MM_ * SS_ * 4;
  float*  encg     = (float*)w;   w += (size_t)BB_ * SS_ * 4;
  float*  pg       = (float*)w;   w += 8192;
  char*   ctl      = w;           w += 16384;  // rowsum[1152] + flags[96*16]
  __bf16* Hx       = (__bf16*)w;  w += (size_t)2 * BB_ * HH_ * 2;  // h exchange dbuf
  float*    rowsum = (float*)ctl;
  unsigned* flags  = (unsigned*)(ctl + 4864);

  // 0) zero rowsum + flags (ws is re-poisoned 0xAA before every call)
  hipMemsetAsync(ctl, 0, 16384, stream);

  // 1) fused preprocessing: 5x fp32->bf16 + build_ws + enc_gate in ONE launch
  prep<<<PREP_TOTAL, 256, 0, stream>>>(embed, enc, wih, whh, hidden, dec, teacher, wgen,
                                       embed_bf, enc_bf, wih_bf, whh_bf, hid_bf, ws_bf, encg);

  // 2) GI = ws @ Wih^T : M=1152, N=2304, K=768
  gemm_bt2<0><<<dim3(2304 / 128, MM_ / 128), 256, 0, stream>>>(ws_bf, wih_bf, GI, nullptr, 2304, 2304);

  // 3) persistent GRU scan (v5: fence-free, sc1 reads + per-wave flags)
  gru_scan<<<NBLK_GRU, 128, 0, stream>>>(hid_bf, hidden, whh_bf, GI, bih, bhh, A_h, Hx, flags);

  // 4) attention + masked softmax + p_gen
  attn_gemm<<<BB_ * 4, 256, 0, stream>>>(A_h, enc_bf, E);
  softmax_pg<<<MM_, 256, 0, stream>>>(E, x, encg, ws_bf, A_h, wgen, wgenb, attn, pg);

  // 5) vocab logits -> exp (nt stores) into d_out + atomic row sums
  gemm_bt2<1><<<dim3((VV_ + 127) / 128, MM_ / 128), 256, 0, stream>>>(A_h, embed_bf, out, rowsum, VV_, VV_);

  // 6) scale by pg/Z in place (f32x2 + nt), then pointer scatter
  finalize<<<dim3(8, MM_), 256, 0, stream>>>(out, rowsum, pg);
  scatter_ctx<<<MM_, 256, 0, stream>>>(out, attn, pg, x);
}